// Round 5
// baseline (210.350 us; speedup 1.0000x reference)
//
#include <hip/hip_runtime.h>
#include <math.h>

#define H2 256
#define MAXDEG 128
#define HPAD 264   // hbuf row stride (elems): 16B-aligned, breaks pow2 banks

typedef __attribute__((ext_vector_type(8))) short bf16x8;
typedef __attribute__((ext_vector_type(4))) float f32x4;

__device__ __forceinline__ unsigned short bf16_rnd(float x) {
    union { float f; unsigned u; } c; c.f = x;
    return (unsigned short)((c.u + 0x7FFFu + ((c.u >> 16) & 1u)) >> 16);
}
__device__ __forceinline__ float bf16_tof(unsigned short h) {
    union { float f; unsigned u; } c; c.u = ((unsigned)h) << 16;
    return c.f;
}
__device__ __forceinline__ void split2(float x, unsigned short& hi, unsigned short& lo) {
    hi = bf16_rnd(x);
    lo = bf16_rnd(x - bf16_tof(hi));
}
__device__ __forceinline__ float u2f_lo(unsigned u) {
    union { float f; unsigned u; } c; c.u = u << 16; return c.f;
}
__device__ __forceinline__ float u2f_hi(unsigned u) {
    union { float f; unsigned u; } c; c.u = u & 0xFFFF0000u; return c.f;
}

// ---------------------------------------------------------------------------
// Fused prep: zero cursor; nf fp32 -> cat hi/lo bf16 cols [0,256);
// W1[512][256]->W1t[256][512] hi/lo; W2[256][256]->W2t[256][256] hi/lo.
__global__ __launch_bounds__(256) void prep(
        const float* __restrict__ nf, const float* __restrict__ W1,
        const float* __restrict__ W2, int* __restrict__ cursor,
        unsigned short* __restrict__ catHi, unsigned short* __restrict__ catLo,
        unsigned short* __restrict__ W1tHi, unsigned short* __restrict__ W1tLo,
        unsigned short* __restrict__ W2tHi, unsigned short* __restrict__ W2tLo,
        int n) {
    int flat = blockIdx.x * 256 + threadIdx.x;
    if (flat < n) cursor[flat] = 0;
    if (flat < 512 * 256) {                    // W1t idx = nn*512 + k
        int nn = flat >> 9, k = flat & 511;
        unsigned short hi, lo;
        split2(W1[(size_t)k * 256 + nn], hi, lo);
        W1tHi[flat] = hi; W1tLo[flat] = lo;
    } else if (flat < 512 * 256 + 256 * 256) { // W2t idx2 = nn*256 + k
        int idx2 = flat - 512 * 256;
        int nn = idx2 >> 8, k = idx2 & 255;
        unsigned short hi, lo;
        split2(W2[(size_t)k * 256 + nn], hi, lo);
        W2tHi[idx2] = hi; W2tLo[idx2] = lo;
    }
    int wid  = threadIdx.x >> 6;
    int lane = threadIdx.x & 63;
    int row  = blockIdx.x * 4 + wid;
    if (row < n) {
        float4 v = ((const float4*)nf)[(size_t)row * 64 + lane];
        ushort4 hi, lo;
        split2(v.x, hi.x, lo.x); split2(v.y, hi.y, lo.y);
        split2(v.z, hi.z, lo.z); split2(v.w, hi.w, lo.w);
        size_t base = (size_t)row * 512 + lane * 4;
        *(ushort4*)&catHi[base] = hi;
        *(ushort4*)&catLo[base] = lo;
    }
}

// ---------------------------------------------------------------------------
__global__ void scatter_edges(const int* __restrict__ esrc, const int* __restrict__ edst,
                              int* __restrict__ cursor, int* __restrict__ bucket, int E) {
    int e = blockIdx.x * 256 + threadIdx.x;
    if (e >= E) return;
    int d = edst[e];
    int s = esrc[e];
    int r = atomicAdd(&cursor[d], 1);
    if (r < MAXDEG) bucket[d * MAXDEG + r] = s;
}

// ---------------------------------------------------------------------------
// pooled[i] = deg_i*nf[i] (fp32) - sum_{src} bf16(nf[src]). 8 gathers in
// flight per iter (bucket row read as 2x int4), 2 independent accumulators.
__global__ __launch_bounds__(256) void agg_kernel(
        const float* __restrict__ nf, const int* __restrict__ cursor,
        const int* __restrict__ bucket, unsigned short* __restrict__ catHi,
        unsigned short* __restrict__ catLo, int n) {
    int wid  = threadIdx.x >> 6;
    int lane = threadIdx.x & 63;
    int node = blockIdx.x * 4 + wid;
    if (node >= n) return;
    int deg  = cursor[node];
    int degc = deg < MAXDEG ? deg : MAXDEG;
    const int* bk = bucket + (size_t)node * MAXDEG;
    float4 accA = make_float4(0.f, 0.f, 0.f, 0.f);
    float4 accB = make_float4(0.f, 0.f, 0.f, 0.f);
    int e = 0;
    for (; e + 8 <= degc; e += 8) {
        int4 sa = *(const int4*)&bk[e];
        int4 sb = *(const int4*)&bk[e + 4];
        uint2 v0 = *(const uint2*)&catHi[(size_t)sa.x * 512 + lane * 4];
        uint2 v1 = *(const uint2*)&catHi[(size_t)sa.y * 512 + lane * 4];
        uint2 v2 = *(const uint2*)&catHi[(size_t)sa.z * 512 + lane * 4];
        uint2 v3 = *(const uint2*)&catHi[(size_t)sa.w * 512 + lane * 4];
        uint2 v4 = *(const uint2*)&catHi[(size_t)sb.x * 512 + lane * 4];
        uint2 v5 = *(const uint2*)&catHi[(size_t)sb.y * 512 + lane * 4];
        uint2 v6 = *(const uint2*)&catHi[(size_t)sb.z * 512 + lane * 4];
        uint2 v7 = *(const uint2*)&catHi[(size_t)sb.w * 512 + lane * 4];
        accA.x += (u2f_lo(v0.x) + u2f_lo(v1.x)) + (u2f_lo(v2.x) + u2f_lo(v3.x));
        accA.y += (u2f_hi(v0.x) + u2f_hi(v1.x)) + (u2f_hi(v2.x) + u2f_hi(v3.x));
        accA.z += (u2f_lo(v0.y) + u2f_lo(v1.y)) + (u2f_lo(v2.y) + u2f_lo(v3.y));
        accA.w += (u2f_hi(v0.y) + u2f_hi(v1.y)) + (u2f_hi(v2.y) + u2f_hi(v3.y));
        accB.x += (u2f_lo(v4.x) + u2f_lo(v5.x)) + (u2f_lo(v6.x) + u2f_lo(v7.x));
        accB.y += (u2f_hi(v4.x) + u2f_hi(v5.x)) + (u2f_hi(v6.x) + u2f_hi(v7.x));
        accB.z += (u2f_lo(v4.y) + u2f_lo(v5.y)) + (u2f_lo(v6.y) + u2f_lo(v7.y));
        accB.w += (u2f_hi(v4.y) + u2f_hi(v5.y)) + (u2f_hi(v6.y) + u2f_hi(v7.y));
    }
    for (; e < degc; ++e) {
        int s = bk[e];
        uint2 v = *(const uint2*)&catHi[(size_t)s * 512 + lane * 4];
        accA.x += u2f_lo(v.x); accA.y += u2f_hi(v.x);
        accA.z += u2f_lo(v.y); accA.w += u2f_hi(v.y);
    }
    float4 self = ((const float4*)nf)[(size_t)node * 64 + lane];
    float fd = (float)deg;
    float4 outv;
    outv.x = fd * self.x - (accA.x + accB.x);
    outv.y = fd * self.y - (accA.y + accB.y);
    outv.z = fd * self.z - (accA.z + accB.z);
    outv.w = fd * self.w - (accA.w + accB.w);
    ushort4 hi, lo;
    split2(outv.x, hi.x, lo.x); split2(outv.y, hi.y, lo.y);
    split2(outv.z, hi.z, lo.z); split2(outv.w, hi.w, lo.w);
    size_t base = (size_t)node * 512 + 256 + lane * 4;
    *(ushort4*)&catHi[base] = hi;
    *(ushort4*)&catLo[base] = lo;
}

// ---------------------------------------------------------------------------
// Fused split-bf16 MFMA GEMM: out = tanh((cat@W1+b1)@W2 + b2).
// 512 thr / 8 waves, M-tile 16 (grid 625 => 4.9 waves/SIMD), wave n-tile 32.
// All fragments direct from global (L2-resident; 4 lanes consume one 64B line
// per W row). h passed stage1->stage2 via 17KB LDS (row stride HPAD=264).
// 3-term split product: Ahi*Bhi + Ahi*Blo + Alo*Bhi.
__global__ __launch_bounds__(512) void gemm12(
        const unsigned short* __restrict__ Ahi, const unsigned short* __restrict__ Alo,
        const unsigned short* __restrict__ W1h, const unsigned short* __restrict__ W1l,
        const unsigned short* __restrict__ W2h, const unsigned short* __restrict__ W2l,
        const float* __restrict__ b1, const float* __restrict__ b2,
        float* __restrict__ out, int M) {
    __shared__ unsigned short hbufH[16 * HPAD], hbufL[16 * HPAD];  // 16.9 KB

    int tid = threadIdx.x, lane = tid & 63, wid = tid >> 6;   // wid 0..7
    int m0 = blockIdx.x * 16;
    int wn = wid * 32;
    int fm = lane & 15;
    int q  = lane >> 4;
    int fk = q * 8;

    // ---- stage 1: h[16][256] = cat[16][512] @ W1t + b1 ----
    int ar = m0 + fm; if (ar >= M) ar = M - 1;   // clamp; junk rows unused
    size_t arow = (size_t)ar * 512 + fk;
    size_t brow[2];
#pragma unroll
    for (int j = 0; j < 2; ++j) brow[j] = (size_t)(wn + j * 16 + fm) * 512 + fk;

    f32x4 acc[2] = {};
#pragma unroll 2
    for (int kb = 0; kb < 512; kb += 32) {
        bf16x8 ah = *(const bf16x8*)&Ahi[arow + kb];
        bf16x8 al = *(const bf16x8*)&Alo[arow + kb];
        bf16x8 bh[2], bl[2];
#pragma unroll
        for (int j = 0; j < 2; ++j) {
            bh[j] = *(const bf16x8*)&W1h[brow[j] + kb];
            bl[j] = *(const bf16x8*)&W1l[brow[j] + kb];
        }
#pragma unroll
        for (int j = 0; j < 2; ++j) {
            acc[j] = __builtin_amdgcn_mfma_f32_16x16x32_bf16(ah, bh[j], acc[j], 0, 0, 0);
            acc[j] = __builtin_amdgcn_mfma_f32_16x16x32_bf16(ah, bl[j], acc[j], 0, 0, 0);
            acc[j] = __builtin_amdgcn_mfma_f32_16x16x32_bf16(al, bh[j], acc[j], 0, 0, 0);
        }
    }

    // epilogue 1: h -> hbuf (row = q*4+r, col = wn + j*16 + fm)
#pragma unroll
    for (int j = 0; j < 2; ++j) {
        int ncol = wn + j * 16 + fm;
        float bv = b1[ncol];
#pragma unroll
        for (int r = 0; r < 4; ++r) {
            int row = q * 4 + r;
            float v = acc[j][r] + bv;
            unsigned short hi, lo;
            split2(v, hi, lo);
            hbufH[row * HPAD + ncol] = hi;
            hbufL[row * HPAD + ncol] = lo;
        }
    }
    __syncthreads();

    // ---- stage 2: out[16][256] = tanh(h @ W2t + b2) ----
    size_t brow2[2];
#pragma unroll
    for (int j = 0; j < 2; ++j) brow2[j] = (size_t)(wn + j * 16 + fm) * 256 + fk;

    f32x4 acc2[2] = {};
#pragma unroll 2
    for (int kb = 0; kb < 256; kb += 32) {
        bf16x8 ah = *(const bf16x8*)&hbufH[fm * HPAD + kb + fk];
        bf16x8 al = *(const bf16x8*)&hbufL[fm * HPAD + kb + fk];
        bf16x8 bh[2], bl[2];
#pragma unroll
        for (int j = 0; j < 2; ++j) {
            bh[j] = *(const bf16x8*)&W2h[brow2[j] + kb];
            bl[j] = *(const bf16x8*)&W2l[brow2[j] + kb];
        }
#pragma unroll
        for (int j = 0; j < 2; ++j) {
            acc2[j] = __builtin_amdgcn_mfma_f32_16x16x32_bf16(ah, bh[j], acc2[j], 0, 0, 0);
            acc2[j] = __builtin_amdgcn_mfma_f32_16x16x32_bf16(ah, bl[j], acc2[j], 0, 0, 0);
            acc2[j] = __builtin_amdgcn_mfma_f32_16x16x32_bf16(al, bh[j], acc2[j], 0, 0, 0);
        }
    }

    // epilogue 2
#pragma unroll
    for (int j = 0; j < 2; ++j) {
        int ncol = wn + j * 16 + fm;
        float bv = b2[ncol];
#pragma unroll
        for (int r = 0; r < 4; ++r) {
            int row = m0 + q * 4 + r;
            if (row < M) out[(size_t)row * 256 + ncol] = tanhf(acc2[j][r] + bv);
        }
    }
}

// ---------------------------------------------------------------------------
extern "C" void kernel_launch(void* const* d_in, const int* in_sizes, int n_in,
                              void* d_out, int out_size, void* d_ws, size_t ws_size,
                              hipStream_t stream) {
    const float* nf  = (const float*)d_in[0];   // [N, 256] fp32
    const float* W1  = (const float*)d_in[1];   // [512, 256]
    const float* b1  = (const float*)d_in[2];   // [256]
    const float* W2  = (const float*)d_in[3];   // [256, 256]
    const float* b2  = (const float*)d_in[4];   // [256]
    const int* esrc  = (const int*)d_in[5];     // [E]
    const int* edst  = (const int*)d_in[6];     // [E]
    float* out = (float*)d_out;                 // [N, 256] fp32

    int N = in_sizes[0] / H2;
    int E = in_sizes[5];

    char* ws = (char*)d_ws;
    size_t off = 0;
    auto take = [&](size_t bytes) { size_t o = off; off += (bytes + 255) / 256 * 256; return o; };
    int*            cursor = (int*)(ws + take((size_t)N * 4));
    int*            bucket = (int*)(ws + take((size_t)N * MAXDEG * 4));
    unsigned short* catHi  = (unsigned short*)(ws + take((size_t)N * 512 * 2));
    unsigned short* catLo  = (unsigned short*)(ws + take((size_t)N * 512 * 2));
    unsigned short* W1tHi  = (unsigned short*)(ws + take(512 * 256 * 2));
    unsigned short* W1tLo  = (unsigned short*)(ws + take(512 * 256 * 2));
    unsigned short* W2tHi  = (unsigned short*)(ws + take(256 * 256 * 2));
    unsigned short* W2tLo  = (unsigned short*)(ws + take(256 * 256 * 2));

    prep<<<(N + 3) / 4, 256, 0, stream>>>(nf, W1, W2, cursor, catHi, catLo,
                                          W1tHi, W1tLo, W2tHi, W2tLo, N);
    scatter_edges<<<(E + 255) / 256, 256, 0, stream>>>(esrc, edst, cursor, bucket, E);
    agg_kernel<<<(N + 3) / 4, 256, 0, stream>>>(nf, cursor, bucket, catHi, catLo, N);
    gemm12<<<(N + 15) / 16, 512, 0, stream>>>(catHi, catLo, W1tHi, W1tLo,
                                              W2tHi, W2tLo, b1, b2, out, N);
}

// Round 6
// 191.422 us; speedup vs baseline: 1.0989x; 1.0989x over previous
//
#include <hip/hip_runtime.h>
#include <math.h>

#define H2 256
#define MAXDEG 128

typedef __attribute__((ext_vector_type(8))) short bf16x8;
typedef __attribute__((ext_vector_type(4))) float f32x4;

__device__ __forceinline__ unsigned short bf16_rnd(float x) {
    union { float f; unsigned u; } c; c.f = x;
    return (unsigned short)((c.u + 0x7FFFu + ((c.u >> 16) & 1u)) >> 16);
}
__device__ __forceinline__ float bf16_tof(unsigned short h) {
    union { float f; unsigned u; } c; c.u = ((unsigned)h) << 16;
    return c.f;
}
__device__ __forceinline__ void split2(float x, unsigned short& hi, unsigned short& lo) {
    hi = bf16_rnd(x);
    lo = bf16_rnd(x - bf16_tof(hi));
}
__device__ __forceinline__ float u2f_lo(unsigned u) {
    union { float f; unsigned u; } c; c.u = u << 16; return c.f;
}
__device__ __forceinline__ float u2f_hi(unsigned u) {
    union { float f; unsigned u; } c; c.u = u & 0xFFFF0000u; return c.f;
}

// ---------------------------------------------------------------------------
// Fused prep: zero cursor; nf fp32 -> cat hi/lo bf16 cols [0,256);
// W1[512][256]->W1t[256][512] hi/lo; W2[256][256]->W2t[256][256] hi/lo.
__global__ __launch_bounds__(256) void prep(
        const float* __restrict__ nf, const float* __restrict__ W1,
        const float* __restrict__ W2, int* __restrict__ cursor,
        unsigned short* __restrict__ catHi, unsigned short* __restrict__ catLo,
        unsigned short* __restrict__ W1tHi, unsigned short* __restrict__ W1tLo,
        unsigned short* __restrict__ W2tHi, unsigned short* __restrict__ W2tLo,
        int n) {
    int flat = blockIdx.x * 256 + threadIdx.x;
    if (flat < n) cursor[flat] = 0;
    if (flat < 512 * 256) {                    // W1t idx = nn*512 + k
        int nn = flat >> 9, k = flat & 511;
        unsigned short hi, lo;
        split2(W1[(size_t)k * 256 + nn], hi, lo);
        W1tHi[flat] = hi; W1tLo[flat] = lo;
    } else if (flat < 512 * 256 + 256 * 256) { // W2t idx2 = nn*256 + k
        int idx2 = flat - 512 * 256;
        int nn = idx2 >> 8, k = idx2 & 255;
        unsigned short hi, lo;
        split2(W2[(size_t)k * 256 + nn], hi, lo);
        W2tHi[idx2] = hi; W2tLo[idx2] = lo;
    }
    int wid  = threadIdx.x >> 6;
    int lane = threadIdx.x & 63;
    int row  = blockIdx.x * 4 + wid;
    if (row < n) {
        float4 v = ((const float4*)nf)[(size_t)row * 64 + lane];
        ushort4 hi, lo;
        split2(v.x, hi.x, lo.x); split2(v.y, hi.y, lo.y);
        split2(v.z, hi.z, lo.z); split2(v.w, hi.w, lo.w);
        size_t base = (size_t)row * 512 + lane * 4;
        *(ushort4*)&catHi[base] = hi;
        *(ushort4*)&catLo[base] = lo;
    }
}

// ---------------------------------------------------------------------------
__global__ void scatter_edges(const int* __restrict__ esrc, const int* __restrict__ edst,
                              int* __restrict__ cursor, int* __restrict__ bucket, int E) {
    int e = blockIdx.x * 256 + threadIdx.x;
    if (e >= E) return;
    int d = edst[e];
    int s = esrc[e];
    int r = atomicAdd(&cursor[d], 1);
    if (r < MAXDEG) bucket[d * MAXDEG + r] = s;
}

// ---------------------------------------------------------------------------
// pooled[i] = deg_i*nf[i] (fp32) - sum_{src} bf16(nf[src]). 8 gathers in
// flight per iter, 2 independent accumulators.
__global__ __launch_bounds__(256) void agg_kernel(
        const float* __restrict__ nf, const int* __restrict__ cursor,
        const int* __restrict__ bucket, unsigned short* __restrict__ catHi,
        unsigned short* __restrict__ catLo, int n) {
    int wid  = threadIdx.x >> 6;
    int lane = threadIdx.x & 63;
    int node = blockIdx.x * 4 + wid;
    if (node >= n) return;
    int deg  = cursor[node];
    int degc = deg < MAXDEG ? deg : MAXDEG;
    const int* bk = bucket + (size_t)node * MAXDEG;
    float4 accA = make_float4(0.f, 0.f, 0.f, 0.f);
    float4 accB = make_float4(0.f, 0.f, 0.f, 0.f);
    int e = 0;
    for (; e + 8 <= degc; e += 8) {
        int4 sa = *(const int4*)&bk[e];
        int4 sb = *(const int4*)&bk[e + 4];
        uint2 v0 = *(const uint2*)&catHi[(size_t)sa.x * 512 + lane * 4];
        uint2 v1 = *(const uint2*)&catHi[(size_t)sa.y * 512 + lane * 4];
        uint2 v2 = *(const uint2*)&catHi[(size_t)sa.z * 512 + lane * 4];
        uint2 v3 = *(const uint2*)&catHi[(size_t)sa.w * 512 + lane * 4];
        uint2 v4 = *(const uint2*)&catHi[(size_t)sb.x * 512 + lane * 4];
        uint2 v5 = *(const uint2*)&catHi[(size_t)sb.y * 512 + lane * 4];
        uint2 v6 = *(const uint2*)&catHi[(size_t)sb.z * 512 + lane * 4];
        uint2 v7 = *(const uint2*)&catHi[(size_t)sb.w * 512 + lane * 4];
        accA.x += (u2f_lo(v0.x) + u2f_lo(v1.x)) + (u2f_lo(v2.x) + u2f_lo(v3.x));
        accA.y += (u2f_hi(v0.x) + u2f_hi(v1.x)) + (u2f_hi(v2.x) + u2f_hi(v3.x));
        accA.z += (u2f_lo(v0.y) + u2f_lo(v1.y)) + (u2f_lo(v2.y) + u2f_lo(v3.y));
        accA.w += (u2f_hi(v0.y) + u2f_hi(v1.y)) + (u2f_hi(v2.y) + u2f_hi(v3.y));
        accB.x += (u2f_lo(v4.x) + u2f_lo(v5.x)) + (u2f_lo(v6.x) + u2f_lo(v7.x));
        accB.y += (u2f_hi(v4.x) + u2f_hi(v5.x)) + (u2f_hi(v6.x) + u2f_hi(v7.x));
        accB.z += (u2f_lo(v4.y) + u2f_lo(v5.y)) + (u2f_lo(v6.y) + u2f_lo(v7.y));
        accB.w += (u2f_hi(v4.y) + u2f_hi(v5.y)) + (u2f_hi(v6.y) + u2f_hi(v7.y));
    }
    for (; e < degc; ++e) {
        int s = bk[e];
        uint2 v = *(const uint2*)&catHi[(size_t)s * 512 + lane * 4];
        accA.x += u2f_lo(v.x); accA.y += u2f_hi(v.x);
        accA.z += u2f_lo(v.y); accA.w += u2f_hi(v.y);
    }
    float4 self = ((const float4*)nf)[(size_t)node * 64 + lane];
    float fd = (float)deg;
    float4 outv;
    outv.x = fd * self.x - (accA.x + accB.x);
    outv.y = fd * self.y - (accA.y + accB.y);
    outv.z = fd * self.z - (accA.z + accB.z);
    outv.w = fd * self.w - (accA.w + accB.w);
    ushort4 hi, lo;
    split2(outv.x, hi.x, lo.x); split2(outv.y, hi.y, lo.y);
    split2(outv.z, hi.z, lo.z); split2(outv.w, hi.w, lo.w);
    size_t base = (size_t)node * 512 + 256 + lane * 4;
    *(ushort4*)&catHi[base] = hi;
    *(ushort4*)&catLo[base] = lo;
}

// ---------------------------------------------------------------------------
// W-stationary split-bf16 MFMA GEMM. Grid (64, 4): block stages its 64-col
// W-slice [64n][K] hi/lo into LDS once (stride KP, 2-way-free banks), then
// 4 waves take distinct 32-row M-chunks (stride 256 workers). Per K-step:
// A hi/lo direct from global (4 b128, each read once chip-wide), B from LDS
// (8 ds_read_b128), 24 mfma 16x16x32. Next-step fragments prefetched into
// registers. 3-term split product: Ahi*Bhi + Ahi*Blo + Alo*Bhi.
template<int K, int KP, bool TANH>
__global__ __launch_bounds__(256, 1) void gemm_lds(
        const unsigned short* __restrict__ Ahi, const unsigned short* __restrict__ Alo,
        const unsigned short* __restrict__ Wh, const unsigned short* __restrict__ Wl,
        const float* __restrict__ bias, float* __restrict__ Cout,
        unsigned short* __restrict__ Chi, unsigned short* __restrict__ Clo, int M) {
    __shared__ unsigned short sH[64 * KP];
    __shared__ unsigned short sL[64 * KP];
    int tid = threadIdx.x, lane = tid & 63, wid = tid >> 6;
    int n0 = blockIdx.y * 64;

    // stage W slice (rows contiguous in W?t[n][k]) -> b128 LDS writes
    constexpr int GPR = K / 8;   // b128 groups per row
    for (int idx = tid; idx < 64 * GPR; idx += 256) {
        int row = idx / GPR;
        int kc  = (idx % GPR) * 8;
        *(uint4*)&sH[row * KP + kc] = *(const uint4*)&Wh[(size_t)(n0 + row) * K + kc];
        *(uint4*)&sL[row * KP + kc] = *(const uint4*)&Wl[(size_t)(n0 + row) * K + kc];
    }
    __syncthreads();

    int fm = lane & 15;
    int q  = lane >> 4;
    int fk = q * 8;
    int nChunks = (M + 31) >> 5;
    int wstride = gridDim.x << 2;

    for (int c = blockIdx.x * 4 + wid; c < nChunks; c += wstride) {
        int m0 = c << 5;
        size_t arow[2];
#pragma unroll
        for (int i = 0; i < 2; ++i) {
            int r = m0 + i * 16 + fm; if (r >= M) r = M - 1;
            arow[i] = (size_t)r * K + fk;
        }
        f32x4 acc[2][4] = {};

        bf16x8 cah[2], cal[2], cbh[4], cbl[4];
#pragma unroll
        for (int i = 0; i < 2; ++i) {
            cah[i] = *(const bf16x8*)&Ahi[arow[i]];
            cal[i] = *(const bf16x8*)&Alo[arow[i]];
        }
#pragma unroll
        for (int j = 0; j < 4; ++j) {
            cbh[j] = *(const bf16x8*)&sH[(j * 16 + fm) * KP + fk];
            cbl[j] = *(const bf16x8*)&sL[(j * 16 + fm) * KP + fk];
        }

        for (int kb = 0; kb < K; kb += 32) {
            bf16x8 nah[2], nal[2], nbh[4], nbl[4];
            int kn = kb + 32;
            if (kn < K) {   // prefetch next step
#pragma unroll
                for (int i = 0; i < 2; ++i) {
                    nah[i] = *(const bf16x8*)&Ahi[arow[i] + kn];
                    nal[i] = *(const bf16x8*)&Alo[arow[i] + kn];
                }
#pragma unroll
                for (int j = 0; j < 4; ++j) {
                    nbh[j] = *(const bf16x8*)&sH[(j * 16 + fm) * KP + kn + fk];
                    nbl[j] = *(const bf16x8*)&sL[(j * 16 + fm) * KP + kn + fk];
                }
            }
#pragma unroll
            for (int i = 0; i < 2; ++i)
#pragma unroll
                for (int j = 0; j < 4; ++j) {
                    acc[i][j] = __builtin_amdgcn_mfma_f32_16x16x32_bf16(cah[i], cbh[j], acc[i][j], 0, 0, 0);
                    acc[i][j] = __builtin_amdgcn_mfma_f32_16x16x32_bf16(cah[i], cbl[j], acc[i][j], 0, 0, 0);
                    acc[i][j] = __builtin_amdgcn_mfma_f32_16x16x32_bf16(cal[i], cbh[j], acc[i][j], 0, 0, 0);
                }
            if (kn < K) {
#pragma unroll
                for (int i = 0; i < 2; ++i) { cah[i] = nah[i]; cal[i] = nal[i]; }
#pragma unroll
                for (int j = 0; j < 4; ++j) { cbh[j] = nbh[j]; cbl[j] = nbl[j]; }
            }
        }

        // epilogue: D row = q*4+r, col = fm (per 16x16 tile)
#pragma unroll
        for (int i = 0; i < 2; ++i)
#pragma unroll
            for (int j = 0; j < 4; ++j) {
                int cn = n0 + j * 16 + fm;
                float bv = bias[cn];
#pragma unroll
                for (int r = 0; r < 4; ++r) {
                    int row = m0 + i * 16 + q * 4 + r;
                    if (row < M) {
                        float v = acc[i][j][r] + bv;
                        if (TANH) {
                            Cout[(size_t)row * 256 + cn] = tanhf(v);
                        } else {
                            unsigned short hi, lo;
                            split2(v, hi, lo);
                            Chi[(size_t)row * 256 + cn] = hi;
                            Clo[(size_t)row * 256 + cn] = lo;
                        }
                    }
                }
            }
    }
}

// ---------------------------------------------------------------------------
extern "C" void kernel_launch(void* const* d_in, const int* in_sizes, int n_in,
                              void* d_out, int out_size, void* d_ws, size_t ws_size,
                              hipStream_t stream) {
    const float* nf  = (const float*)d_in[0];   // [N, 256] fp32
    const float* W1  = (const float*)d_in[1];   // [512, 256]
    const float* b1  = (const float*)d_in[2];   // [256]
    const float* W2  = (const float*)d_in[3];   // [256, 256]
    const float* b2  = (const float*)d_in[4];   // [256]
    const int* esrc  = (const int*)d_in[5];     // [E]
    const int* edst  = (const int*)d_in[6];     // [E]
    float* out = (float*)d_out;                 // [N, 256] fp32

    int N = in_sizes[0] / H2;
    int E = in_sizes[5];

    char* ws = (char*)d_ws;
    size_t off = 0;
    auto take = [&](size_t bytes) { size_t o = off; off += (bytes + 255) / 256 * 256; return o; };
    int*            cursor = (int*)(ws + take((size_t)N * 4));
    int*            bucket = (int*)(ws + take((size_t)N * MAXDEG * 4));
    unsigned short* catHi  = (unsigned short*)(ws + take((size_t)N * 512 * 2));
    unsigned short* catLo  = (unsigned short*)(ws + take((size_t)N * 512 * 2));
    unsigned short* W1tHi  = (unsigned short*)(ws + take(512 * 256 * 2));
    unsigned short* W1tLo  = (unsigned short*)(ws + take(512 * 256 * 2));
    unsigned short* W2tHi  = (unsigned short*)(ws + take(256 * 256 * 2));
    unsigned short* W2tLo  = (unsigned short*)(ws + take(256 * 256 * 2));
    unsigned short* hHi    = (unsigned short*)(ws + take((size_t)N * 256 * 2));
    unsigned short* hLo    = (unsigned short*)(ws + take((size_t)N * 256 * 2));

    prep<<<(N + 3) / 4, 256, 0, stream>>>(nf, W1, W2, cursor, catHi, catLo,
                                          W1tHi, W1tLo, W2tHi, W2tLo, N);
    scatter_edges<<<(E + 255) / 256, 256, 0, stream>>>(esrc, edst, cursor, bucket, E);
    agg_kernel<<<(N + 3) / 4, 256, 0, stream>>>(nf, cursor, bucket, catHi, catLo, N);

    dim3 g(64, 4);
    gemm_lds<512, 520, false><<<g, 256, 0, stream>>>(catHi, catLo, W1tHi, W1tLo,
                                                     b1, nullptr, hHi, hLo, N);
    gemm_lds<256, 264, true><<<g, 256, 0, stream>>>(hHi, hLo, W2tHi, W2tLo,
                                                    b2, out, nullptr, nullptr, N);
}

// Round 7
// 161.553 us; speedup vs baseline: 1.3021x; 1.1849x over previous
//
#include <hip/hip_runtime.h>
#include <math.h>

#define H2 256
#define MAXDEG 128
#define HPAD 264   // hbuf row stride in halves; 528B rows -> 2-way banks (free)

typedef _Float16 f16x8 __attribute__((ext_vector_type(8)));
typedef _Float16 f16x4 __attribute__((ext_vector_type(4)));
typedef float f32x4 __attribute__((ext_vector_type(4)));

// ---------------------------------------------------------------------------
// Fused prep: zero cursor; nf fp32 -> cat fp16 cols [0,256);
// W1[512][256]->W1t[256][512] fp16; W2[256][256]->W2t[256][256] fp16.
__global__ __launch_bounds__(256) void prep(
        const float* __restrict__ nf, const float* __restrict__ W1,
        const float* __restrict__ W2, int* __restrict__ cursor,
        _Float16* __restrict__ cat, _Float16* __restrict__ W1t,
        _Float16* __restrict__ W2t, int n) {
    int flat = blockIdx.x * 256 + threadIdx.x;
    if (flat < n) cursor[flat] = 0;
    if (flat < 512 * 256) {                    // W1t idx = nn*512 + k
        int nn = flat >> 9, k = flat & 511;
        W1t[flat] = (_Float16)W1[(size_t)k * 256 + nn];
    } else if (flat < 512 * 256 + 256 * 256) { // W2t idx2 = nn*256 + k
        int idx2 = flat - 512 * 256;
        int nn = idx2 >> 8, k = idx2 & 255;
        W2t[idx2] = (_Float16)W2[(size_t)k * 256 + nn];
    }
    int wid  = threadIdx.x >> 6;
    int lane = threadIdx.x & 63;
    int row  = blockIdx.x * 4 + wid;
    if (row < n) {
        float4 v = ((const float4*)nf)[(size_t)row * 64 + lane];
        f16x4 h;
        h.x = (_Float16)v.x; h.y = (_Float16)v.y;
        h.z = (_Float16)v.z; h.w = (_Float16)v.w;
        *(f16x4*)&cat[(size_t)row * 512 + lane * 4] = h;
    }
}

// ---------------------------------------------------------------------------
__global__ void scatter_edges(const int* __restrict__ esrc, const int* __restrict__ edst,
                              int* __restrict__ cursor, int* __restrict__ bucket, int E) {
    int e = blockIdx.x * 256 + threadIdx.x;
    if (e >= E) return;
    int d = edst[e];
    int s = esrc[e];
    int r = atomicAdd(&cursor[d], 1);
    if (r < MAXDEG) bucket[d * MAXDEG + r] = s;
}

// ---------------------------------------------------------------------------
// pooled[i] = deg_i*nf[i] (fp32) - sum_{src} fp16(nf[src]); gathers 8B/lane
// fp16 rows from cat cols [0,256); writes fp16 into cat cols [256,512).
// 8 gathers in flight per iter, 2 independent accumulators.
__global__ __launch_bounds__(256) void agg_kernel(
        const float* __restrict__ nf, const int* __restrict__ cursor,
        const int* __restrict__ bucket, _Float16* __restrict__ cat, int n) {
    int wid  = threadIdx.x >> 6;
    int lane = threadIdx.x & 63;
    int node = blockIdx.x * 4 + wid;
    if (node >= n) return;
    int deg  = cursor[node];
    int degc = deg < MAXDEG ? deg : MAXDEG;
    const int* bk = bucket + (size_t)node * MAXDEG;
    float4 accA = make_float4(0.f, 0.f, 0.f, 0.f);
    float4 accB = make_float4(0.f, 0.f, 0.f, 0.f);
    int e = 0;
    for (; e + 8 <= degc; e += 8) {
        int4 sa = *(const int4*)&bk[e];
        int4 sb = *(const int4*)&bk[e + 4];
        f16x4 v0 = *(const f16x4*)&cat[(size_t)sa.x * 512 + lane * 4];
        f16x4 v1 = *(const f16x4*)&cat[(size_t)sa.y * 512 + lane * 4];
        f16x4 v2 = *(const f16x4*)&cat[(size_t)sa.z * 512 + lane * 4];
        f16x4 v3 = *(const f16x4*)&cat[(size_t)sa.w * 512 + lane * 4];
        f16x4 v4 = *(const f16x4*)&cat[(size_t)sb.x * 512 + lane * 4];
        f16x4 v5 = *(const f16x4*)&cat[(size_t)sb.y * 512 + lane * 4];
        f16x4 v6 = *(const f16x4*)&cat[(size_t)sb.z * 512 + lane * 4];
        f16x4 v7 = *(const f16x4*)&cat[(size_t)sb.w * 512 + lane * 4];
        accA.x += ((float)v0.x + (float)v1.x) + ((float)v2.x + (float)v3.x);
        accA.y += ((float)v0.y + (float)v1.y) + ((float)v2.y + (float)v3.y);
        accA.z += ((float)v0.z + (float)v1.z) + ((float)v2.z + (float)v3.z);
        accA.w += ((float)v0.w + (float)v1.w) + ((float)v2.w + (float)v3.w);
        accB.x += ((float)v4.x + (float)v5.x) + ((float)v6.x + (float)v7.x);
        accB.y += ((float)v4.y + (float)v5.y) + ((float)v6.y + (float)v7.y);
        accB.z += ((float)v4.z + (float)v5.z) + ((float)v6.z + (float)v7.z);
        accB.w += ((float)v4.w + (float)v5.w) + ((float)v6.w + (float)v7.w);
    }
    for (; e < degc; ++e) {
        int s = bk[e];
        f16x4 v = *(const f16x4*)&cat[(size_t)s * 512 + lane * 4];
        accA.x += (float)v.x; accA.y += (float)v.y;
        accA.z += (float)v.z; accA.w += (float)v.w;
    }
    float4 self = ((const float4*)nf)[(size_t)node * 64 + lane];
    float fd = (float)deg;
    f16x4 o;
    o.x = (_Float16)(fd * self.x - (accA.x + accB.x));
    o.y = (_Float16)(fd * self.y - (accA.y + accB.y));
    o.z = (_Float16)(fd * self.z - (accA.z + accB.z));
    o.w = (_Float16)(fd * self.w - (accA.w + accB.w));
    *(f16x4*)&cat[(size_t)node * 512 + 256 + lane * 4] = o;
}

// ---------------------------------------------------------------------------
// Fused single-product fp16 MFMA GEMM: out = tanh((cat@W1+b1)@W2 + b2).
// 512 thr / 8 waves; M-tile 32 (grid 313); wave w owns n-cols [32w, 32w+32).
// A and W fragments direct from global: A-tile (32KB) is L1-resident and
// reused by all 8 waves; W1t/W2t are L2-resident. h passes stage1->stage2
// via 17KB LDS (stride HPAD=264 halves -> 2-way-free banks).
__global__ __launch_bounds__(512, 4) void gemm12(
        const _Float16* __restrict__ cat, const _Float16* __restrict__ W1t,
        const _Float16* __restrict__ W2t, const float* __restrict__ b1,
        const float* __restrict__ b2, float* __restrict__ out, int M) {
    __shared__ _Float16 hbuf[32 * HPAD];   // 16896 B

    int tid = threadIdx.x, lane = tid & 63, wid = tid >> 6;   // wid 0..7
    int m0 = blockIdx.x * 32;
    int wn = wid * 32;
    int fm = lane & 15;
    int q  = lane >> 4;
    int fk = q * 8;

    // ---- stage 1: h[32][256] = cat[32][512] @ W1t + b1 ----
    size_t arow[2], brow[2];
#pragma unroll
    for (int i = 0; i < 2; ++i) {
        int r = m0 + i * 16 + fm; if (r >= M) r = M - 1;   // clamp; junk guarded at store
        arow[i] = (size_t)r * 512 + fk;
    }
#pragma unroll
    for (int j = 0; j < 2; ++j) brow[j] = (size_t)(wn + j * 16 + fm) * 512 + fk;

    f32x4 acc[2][2] = {};
#pragma unroll 2
    for (int kb = 0; kb < 512; kb += 32) {
        f16x8 a[2], b[2];
#pragma unroll
        for (int i = 0; i < 2; ++i) a[i] = *(const f16x8*)&cat[arow[i] + kb];
#pragma unroll
        for (int j = 0; j < 2; ++j) b[j] = *(const f16x8*)&W1t[brow[j] + kb];
#pragma unroll
        for (int i = 0; i < 2; ++i)
#pragma unroll
            for (int j = 0; j < 2; ++j)
                acc[i][j] = __builtin_amdgcn_mfma_f32_16x16x32_f16(a[i], b[j], acc[i][j], 0, 0, 0);
    }

    // epilogue 1: h -> hbuf[row][ncol]  (row = i*16+q*4+r, ncol = wn+j*16+fm)
#pragma unroll
    for (int j = 0; j < 2; ++j) {
        int ncol = wn + j * 16 + fm;
        float bv = b1[ncol];
#pragma unroll
        for (int i = 0; i < 2; ++i)
#pragma unroll
            for (int r = 0; r < 4; ++r)
                hbuf[(i * 16 + q * 4 + r) * HPAD + ncol] = (_Float16)(acc[i][j][r] + bv);
    }
    __syncthreads();

    // ---- stage 2: out[32][256] = tanh(h @ W2t + b2) ----
    size_t brow2[2];
#pragma unroll
    for (int j = 0; j < 2; ++j) brow2[j] = (size_t)(wn + j * 16 + fm) * 256 + fk;

    f32x4 acc2[2][2] = {};
#pragma unroll 2
    for (int kb = 0; kb < 256; kb += 32) {
        f16x8 a[2], b[2];
#pragma unroll
        for (int i = 0; i < 2; ++i)
            a[i] = *(const f16x8*)&hbuf[(i * 16 + fm) * HPAD + kb + fk];
#pragma unroll
        for (int j = 0; j < 2; ++j) b[j] = *(const f16x8*)&W2t[brow2[j] + kb];
#pragma unroll
        for (int i = 0; i < 2; ++i)
#pragma unroll
            for (int j = 0; j < 2; ++j)
                acc2[i][j] = __builtin_amdgcn_mfma_f32_16x16x32_f16(a[i], b[j], acc2[i][j], 0, 0, 0);
    }

    // epilogue 2
#pragma unroll
    for (int j = 0; j < 2; ++j) {
        int ncol = wn + j * 16 + fm;
        float bv = b2[ncol];
#pragma unroll
        for (int i = 0; i < 2; ++i)
#pragma unroll
            for (int r = 0; r < 4; ++r) {
                int row = m0 + i * 16 + q * 4 + r;
                if (row < M) out[(size_t)row * 256 + ncol] = tanhf(acc2[i][j][r] + bv);
            }
    }
}

// ---------------------------------------------------------------------------
extern "C" void kernel_launch(void* const* d_in, const int* in_sizes, int n_in,
                              void* d_out, int out_size, void* d_ws, size_t ws_size,
                              hipStream_t stream) {
    const float* nf  = (const float*)d_in[0];   // [N, 256] fp32
    const float* W1  = (const float*)d_in[1];   // [512, 256]
    const float* b1  = (const float*)d_in[2];   // [256]
    const float* W2  = (const float*)d_in[3];   // [256, 256]
    const float* b2  = (const float*)d_in[4];   // [256]
    const int* esrc  = (const int*)d_in[5];     // [E]
    const int* edst  = (const int*)d_in[6];     // [E]
    float* out = (float*)d_out;                 // [N, 256] fp32

    int N = in_sizes[0] / H2;
    int E = in_sizes[5];

    char* ws = (char*)d_ws;
    size_t off = 0;
    auto take = [&](size_t bytes) { size_t o = off; off += (bytes + 255) / 256 * 256; return o; };
    int*       cursor = (int*)(ws + take((size_t)N * 4));
    int*       bucket = (int*)(ws + take((size_t)N * MAXDEG * 4));
    _Float16*  cat    = (_Float16*)(ws + take((size_t)N * 512 * 2));
    _Float16*  W1t    = (_Float16*)(ws + take(512 * 256 * 2));
    _Float16*  W2t    = (_Float16*)(ws + take(256 * 256 * 2));

    prep<<<(N + 3) / 4, 256, 0, stream>>>(nf, W1, W2, cursor, cat, W1t, W2t, N);
    scatter_edges<<<(E + 255) / 256, 256, 0, stream>>>(esrc, edst, cursor, bucket, E);
    agg_kernel<<<(N + 3) / 4, 256, 0, stream>>>(nf, cursor, bucket, cat, N);
    gemm12<<<(N + 31) / 32, 512, 0, stream>>>(cat, W1t, W2t, b1, b2, out, N);
}

// Round 8
// 157.619 us; speedup vs baseline: 1.3345x; 1.0250x over previous
//
#include <hip/hip_runtime.h>
#include <math.h>

#define H2 256
#define MAXDEG 128
#define APAD 520   // sA row stride (halves): 1040B rows -> 2-way banks (free)
#define HPAD 264   // hbuf row stride (halves): 528B rows -> 2-way banks (free)

typedef _Float16 f16x8 __attribute__((ext_vector_type(8)));
typedef _Float16 f16x4 __attribute__((ext_vector_type(4)));
typedef float f32x4 __attribute__((ext_vector_type(4)));

// ---------------------------------------------------------------------------
// Fused prep: zero cursor; nf fp32 -> cat fp16 cols [0,256);
// W1[512][256]->W1t[256][512] fp16; W2[256][256]->W2t[256][256] fp16.
__global__ __launch_bounds__(256) void prep(
        const float* __restrict__ nf, const float* __restrict__ W1,
        const float* __restrict__ W2, int* __restrict__ cursor,
        _Float16* __restrict__ cat, _Float16* __restrict__ W1t,
        _Float16* __restrict__ W2t, int n) {
    int flat = blockIdx.x * 256 + threadIdx.x;
    if (flat < n) cursor[flat] = 0;
    if (flat < 512 * 256) {                    // W1t idx = nn*512 + k
        int nn = flat >> 9, k = flat & 511;
        W1t[flat] = (_Float16)W1[(size_t)k * 256 + nn];
    } else if (flat < 512 * 256 + 256 * 256) { // W2t idx2 = nn*256 + k
        int idx2 = flat - 512 * 256;
        int nn = idx2 >> 8, k = idx2 & 255;
        W2t[idx2] = (_Float16)W2[(size_t)k * 256 + nn];
    }
    int wid  = threadIdx.x >> 6;
    int lane = threadIdx.x & 63;
    int row  = blockIdx.x * 4 + wid;
    if (row < n) {
        float4 v = ((const float4*)nf)[(size_t)row * 64 + lane];
        f16x4 h;
        h.x = (_Float16)v.x; h.y = (_Float16)v.y;
        h.z = (_Float16)v.z; h.w = (_Float16)v.w;
        *(f16x4*)&cat[(size_t)row * 512 + lane * 4] = h;
    }
}

// ---------------------------------------------------------------------------
__global__ void scatter_edges(const int* __restrict__ esrc, const int* __restrict__ edst,
                              int* __restrict__ cursor, int* __restrict__ bucket, int E) {
    int e = blockIdx.x * 256 + threadIdx.x;
    if (e >= E) return;
    int d = edst[e];
    int s = esrc[e];
    int r = atomicAdd(&cursor[d], 1);
    if (r < MAXDEG) bucket[d * MAXDEG + r] = s;
}

// ---------------------------------------------------------------------------
// pooled[i] = deg_i*nf[i] (fp32) - sum_{src} fp16(nf[src]); gathers 8B/lane
// fp16 rows from cat cols [0,256); writes fp16 into cat cols [256,512).
__global__ __launch_bounds__(256) void agg_kernel(
        const float* __restrict__ nf, const int* __restrict__ cursor,
        const int* __restrict__ bucket, _Float16* __restrict__ cat, int n) {
    int wid  = threadIdx.x >> 6;
    int lane = threadIdx.x & 63;
    int node = blockIdx.x * 4 + wid;
    if (node >= n) return;
    int deg  = cursor[node];
    int degc = deg < MAXDEG ? deg : MAXDEG;
    const int* bk = bucket + (size_t)node * MAXDEG;
    float4 accA = make_float4(0.f, 0.f, 0.f, 0.f);
    float4 accB = make_float4(0.f, 0.f, 0.f, 0.f);
    int e = 0;
    for (; e + 8 <= degc; e += 8) {
        int4 sa = *(const int4*)&bk[e];
        int4 sb = *(const int4*)&bk[e + 4];
        f16x4 v0 = *(const f16x4*)&cat[(size_t)sa.x * 512 + lane * 4];
        f16x4 v1 = *(const f16x4*)&cat[(size_t)sa.y * 512 + lane * 4];
        f16x4 v2 = *(const f16x4*)&cat[(size_t)sa.z * 512 + lane * 4];
        f16x4 v3 = *(const f16x4*)&cat[(size_t)sa.w * 512 + lane * 4];
        f16x4 v4 = *(const f16x4*)&cat[(size_t)sb.x * 512 + lane * 4];
        f16x4 v5 = *(const f16x4*)&cat[(size_t)sb.y * 512 + lane * 4];
        f16x4 v6 = *(const f16x4*)&cat[(size_t)sb.z * 512 + lane * 4];
        f16x4 v7 = *(const f16x4*)&cat[(size_t)sb.w * 512 + lane * 4];
        accA.x += ((float)v0.x + (float)v1.x) + ((float)v2.x + (float)v3.x);
        accA.y += ((float)v0.y + (float)v1.y) + ((float)v2.y + (float)v3.y);
        accA.z += ((float)v0.z + (float)v1.z) + ((float)v2.z + (float)v3.z);
        accA.w += ((float)v0.w + (float)v1.w) + ((float)v2.w + (float)v3.w);
        accB.x += ((float)v4.x + (float)v5.x) + ((float)v6.x + (float)v7.x);
        accB.y += ((float)v4.y + (float)v5.y) + ((float)v6.y + (float)v7.y);
        accB.z += ((float)v4.z + (float)v5.z) + ((float)v6.z + (float)v7.z);
        accB.w += ((float)v4.w + (float)v5.w) + ((float)v6.w + (float)v7.w);
    }
    for (; e < degc; ++e) {
        int s = bk[e];
        f16x4 v = *(const f16x4*)&cat[(size_t)s * 512 + lane * 4];
        accA.x += (float)v.x; accA.y += (float)v.y;
        accA.z += (float)v.z; accA.w += (float)v.w;
    }
    float4 self = ((const float4*)nf)[(size_t)node * 64 + lane];
    float fd = (float)deg;
    f16x4 o;
    o.x = (_Float16)(fd * self.x - (accA.x + accB.x));
    o.y = (_Float16)(fd * self.y - (accA.y + accB.y));
    o.z = (_Float16)(fd * self.z - (accA.z + accB.z));
    o.w = (_Float16)(fd * self.w - (accA.w + accB.w));
    *(f16x4*)&cat[(size_t)node * 512 + 256 + lane * 4] = o;
}

// ---------------------------------------------------------------------------
// Fused fp16 MFMA GEMM: out = tanh((cat@W1+b1)@W2 + b2).
// 512 thr / 8 waves; M-tile 16 (grid 625 -> 4.9 waves/SIMD); wave n-tile 32.
// A-tile staged once into LDS (APAD=520, coalesced b128); W fragments direct
// from L2 with one-step register prefetch; h via LDS (HPAD=264).
__global__ __launch_bounds__(512, 4) void gemm12(
        const _Float16* __restrict__ cat, const _Float16* __restrict__ W1t,
        const _Float16* __restrict__ W2t, const float* __restrict__ b1,
        const float* __restrict__ b2, float* __restrict__ out, int M) {
    __shared__ _Float16 sA[16 * APAD];     // 16.3 KB
    __shared__ _Float16 hbuf[16 * HPAD];   //  8.3 KB

    int tid = threadIdx.x, lane = tid & 63, wid = tid >> 6;   // wid 0..7
    int m0 = blockIdx.x * 16;
    int wn = wid * 32;
    int fm = lane & 15;
    int q  = lane >> 4;
    int fk = q * 8;

    // stage A: 16 rows x 512 cols fp16; 1024 b128-groups; 2 passes of 512 thr
    for (int idx = tid; idx < 16 * 64; idx += 512) {
        int row = idx >> 6, g = (idx & 63) * 8;
        int r = m0 + row; if (r >= M) r = M - 1;   // clamp; junk rows unused
        *(uint4*)&sA[row * APAD + g] = *(const uint4*)&cat[(size_t)r * 512 + g];
    }
    __syncthreads();

    // ---- stage 1: h[16][256] = A @ W1t + b1 ----
    size_t brow[2];
#pragma unroll
    for (int j = 0; j < 2; ++j) brow[j] = (size_t)(wn + j * 16 + fm) * 512 + fk;

    f32x4 acc[2] = {};
    f16x8 bc[2], bn[2];
#pragma unroll
    for (int j = 0; j < 2; ++j) bc[j] = *(const f16x8*)&W1t[brow[j]];
    for (int kb = 0; kb < 512; kb += 32) {
        int kn = kb + 32;
        if (kn < 512) {
#pragma unroll
            for (int j = 0; j < 2; ++j) bn[j] = *(const f16x8*)&W1t[brow[j] + kn];
        }
        f16x8 a = *(const f16x8*)&sA[fm * APAD + kb + fk];
#pragma unroll
        for (int j = 0; j < 2; ++j)
            acc[j] = __builtin_amdgcn_mfma_f32_16x16x32_f16(a, bc[j], acc[j], 0, 0, 0);
        if (kn < 512) {
#pragma unroll
            for (int j = 0; j < 2; ++j) bc[j] = bn[j];
        }
    }

    // epilogue 1: hbuf[row][ncol], row = q*4+r, ncol = wn + j*16 + fm
#pragma unroll
    for (int j = 0; j < 2; ++j) {
        int ncol = wn + j * 16 + fm;
        float bv = b1[ncol];
#pragma unroll
        for (int r = 0; r < 4; ++r)
            hbuf[(q * 4 + r) * HPAD + ncol] = (_Float16)(acc[j][r] + bv);
    }
    __syncthreads();

    // ---- stage 2: out[16][256] = tanh(h @ W2t + b2) ----
    size_t brow2[2];
#pragma unroll
    for (int j = 0; j < 2; ++j) brow2[j] = (size_t)(wn + j * 16 + fm) * 256 + fk;

    f32x4 acc2[2] = {};
#pragma unroll
    for (int j = 0; j < 2; ++j) bc[j] = *(const f16x8*)&W2t[brow2[j]];
    for (int kb = 0; kb < 256; kb += 32) {
        int kn = kb + 32;
        if (kn < 256) {
#pragma unroll
            for (int j = 0; j < 2; ++j) bn[j] = *(const f16x8*)&W2t[brow2[j] + kn];
        }
        f16x8 a = *(const f16x8*)&hbuf[fm * HPAD + kb + fk];
#pragma unroll
        for (int j = 0; j < 2; ++j)
            acc2[j] = __builtin_amdgcn_mfma_f32_16x16x32_f16(a, bc[j], acc2[j], 0, 0, 0);
        if (kn < 256) {
#pragma unroll
            for (int j = 0; j < 2; ++j) bc[j] = bn[j];
        }
    }

    // epilogue 2
#pragma unroll
    for (int j = 0; j < 2; ++j) {
        int ncol = wn + j * 16 + fm;
        float bv = b2[ncol];
#pragma unroll
        for (int r = 0; r < 4; ++r) {
            int row = m0 + q * 4 + r;
            if (row < M) out[(size_t)row * 256 + ncol] = tanhf(acc2[j][r] + bv);
        }
    }
}

// ---------------------------------------------------------------------------
extern "C" void kernel_launch(void* const* d_in, const int* in_sizes, int n_in,
                              void* d_out, int out_size, void* d_ws, size_t ws_size,
                              hipStream_t stream) {
    const float* nf  = (const float*)d_in[0];   // [N, 256] fp32
    const float* W1  = (const float*)d_in[1];   // [512, 256]
    const float* b1  = (const float*)d_in[2];   // [256]
    const float* W2  = (const float*)d_in[3];   // [256, 256]
    const float* b2  = (const float*)d_in[4];   // [256]
    const int* esrc  = (const int*)d_in[5];     // [E]
    const int* edst  = (const int*)d_in[6];     // [E]
    float* out = (float*)d_out;                 // [N, 256] fp32

    int N = in_sizes[0] / H2;
    int E = in_sizes[5];

    char* ws = (char*)d_ws;
    size_t off = 0;
    auto take = [&](size_t bytes) { size_t o = off; off += (bytes + 255) / 256 * 256; return o; };
    int*       cursor = (int*)(ws + take((size_t)N * 4));
    int*       bucket = (int*)(ws + take((size_t)N * MAXDEG * 4));
    _Float16*  cat    = (_Float16*)(ws + take((size_t)N * 512 * 2));
    _Float16*  W1t    = (_Float16*)(ws + take(512 * 256 * 2));
    _Float16*  W2t    = (_Float16*)(ws + take(256 * 256 * 2));

    prep<<<(N + 3) / 4, 256, 0, stream>>>(nf, W1, W2, cursor, cat, W1t, W2t, N);
    scatter_edges<<<(E + 255) / 256, 256, 0, stream>>>(esrc, edst, cursor, bucket, E);
    agg_kernel<<<(N + 3) / 4, 256, 0, stream>>>(nf, cursor, bucket, cat, N);
    gemm12<<<(N + 15) / 16, 512, 0, stream>>>(cat, W1t, W2t, b1, b2, out, N);
}

// Round 9
// 152.928 us; speedup vs baseline: 1.3755x; 1.0307x over previous
//
#include <hip/hip_runtime.h>
#include <math.h>

#define H2 256
#define MAXDEG 128
#define APAD 520   // sA row stride (halves): 1040B rows -> 2-way banks (free)
#define HPAD 264   // hbuf row stride (halves): 528B rows -> 2-way banks (free)

typedef _Float16 f16x8 __attribute__((ext_vector_type(8)));
typedef _Float16 f16x4 __attribute__((ext_vector_type(4)));
typedef float f32x4 __attribute__((ext_vector_type(4)));

// ---------------------------------------------------------------------------
// Fused prep: zero cursor; nf fp32 -> cat fp16 [N][256];
// W1[512][256]->W1t[256][512] fp16; W2[256][256]->W2t[256][256] fp16.
__global__ __launch_bounds__(256) void prep(
        const float* __restrict__ nf, const float* __restrict__ W1,
        const float* __restrict__ W2, int* __restrict__ cursor,
        _Float16* __restrict__ cat, _Float16* __restrict__ W1t,
        _Float16* __restrict__ W2t, int n) {
    int flat = blockIdx.x * 256 + threadIdx.x;
    if (flat < n) cursor[flat] = 0;
    if (flat < 512 * 256) {                    // W1t idx = nn*512 + k
        int nn = flat >> 9, k = flat & 511;
        W1t[flat] = (_Float16)W1[(size_t)k * 256 + nn];
    } else if (flat < 512 * 256 + 256 * 256) { // W2t idx2 = nn*256 + k
        int idx2 = flat - 512 * 256;
        int nn = idx2 >> 8, k = idx2 & 255;
        W2t[idx2] = (_Float16)W2[(size_t)k * 256 + nn];
    }
    int wid  = threadIdx.x >> 6;
    int lane = threadIdx.x & 63;
    int row  = blockIdx.x * 4 + wid;
    if (row < n) {
        float4 v = ((const float4*)nf)[(size_t)row * 64 + lane];
        f16x4 h;
        h.x = (_Float16)v.x; h.y = (_Float16)v.y;
        h.z = (_Float16)v.z; h.w = (_Float16)v.w;
        *(f16x4*)&cat[(size_t)row * 256 + lane * 4] = h;
    }
}

// ---------------------------------------------------------------------------
__global__ void scatter_edges(const int* __restrict__ esrc, const int* __restrict__ edst,
                              int* __restrict__ cursor, int* __restrict__ bucket, int E) {
    int e = blockIdx.x * 256 + threadIdx.x;
    if (e >= E) return;
    int d = edst[e];
    int s = esrc[e];
    int r = atomicAdd(&cursor[d], 1);
    if (r < MAXDEG) bucket[d * MAXDEG + r] = s;
}

// ---------------------------------------------------------------------------
// Fully fused: gather pooled for this block's 16 rows into LDS, then
// out = tanh(([nf16 | pooled] @ W1t + b1) @ W2t + b2).
// 512 thr / 8 waves; M-tile 16 (grid 625 -> 4.9 waves/SIMD); wave n-tile 32.
// Phase 0a: stage cat rows -> sA cols [0,256).
// Phase 0b: wave w gathers pooled for rows 2w,2w+1 (MLP-8 over bucket),
//           writes fp16 into sA cols [256,512). One __syncthreads.
// Stages 1/2: W fragments from L2 via depth-4 register pipeline; A via LDS
// with 1-step prefetch; h via LDS (HPAD).
__global__ __launch_bounds__(512, 4) void gemm12agg(
        const float* __restrict__ nf, const _Float16* __restrict__ cat,
        const int* __restrict__ cursor, const int* __restrict__ bucket,
        const _Float16* __restrict__ W1t, const _Float16* __restrict__ W2t,
        const float* __restrict__ b1, const float* __restrict__ b2,
        float* __restrict__ out, int M) {
    __shared__ _Float16 sA[16 * APAD];     // 16.3 KB
    __shared__ _Float16 hbuf[16 * HPAD];   //  8.3 KB

    int tid = threadIdx.x, lane = tid & 63, wid = tid >> 6;   // wid 0..7
    int m0 = blockIdx.x * 16;
    int wn = wid * 32;
    int fm = lane & 15;
    int q  = lane >> 4;
    int fk = q * 8;

    // ---- phase 0a: stage cat -> sA cols [0,256): 16 rows x 32 b128 groups
    {
        int row = tid >> 5, g = (tid & 31) * 8;
        int r = m0 + row; if (r >= M) r = M - 1;
        *(uint4*)&sA[row * APAD + g] = *(const uint4*)&cat[(size_t)r * 256 + g];
    }

    // ---- phase 0b: gather pooled for rows 2*wid, 2*wid+1
#pragma unroll
    for (int t = 0; t < 2; ++t) {
        int rw = wid * 2 + t;
        int node = m0 + rw; if (node >= M) node = M - 1;
        int deg  = cursor[node];
        int degc = deg < MAXDEG ? deg : MAXDEG;
        const int* bk = bucket + (size_t)node * MAXDEG;
        float4 accA = make_float4(0.f, 0.f, 0.f, 0.f);
        float4 accB = make_float4(0.f, 0.f, 0.f, 0.f);
        int e = 0;
        for (; e + 8 <= degc; e += 8) {
            int4 sa = *(const int4*)&bk[e];
            int4 sb = *(const int4*)&bk[e + 4];
            f16x4 v0 = *(const f16x4*)&cat[(size_t)sa.x * 256 + lane * 4];
            f16x4 v1 = *(const f16x4*)&cat[(size_t)sa.y * 256 + lane * 4];
            f16x4 v2 = *(const f16x4*)&cat[(size_t)sa.z * 256 + lane * 4];
            f16x4 v3 = *(const f16x4*)&cat[(size_t)sa.w * 256 + lane * 4];
            f16x4 v4 = *(const f16x4*)&cat[(size_t)sb.x * 256 + lane * 4];
            f16x4 v5 = *(const f16x4*)&cat[(size_t)sb.y * 256 + lane * 4];
            f16x4 v6 = *(const f16x4*)&cat[(size_t)sb.z * 256 + lane * 4];
            f16x4 v7 = *(const f16x4*)&cat[(size_t)sb.w * 256 + lane * 4];
            accA.x += ((float)v0.x + (float)v1.x) + ((float)v2.x + (float)v3.x);
            accA.y += ((float)v0.y + (float)v1.y) + ((float)v2.y + (float)v3.y);
            accA.z += ((float)v0.z + (float)v1.z) + ((float)v2.z + (float)v3.z);
            accA.w += ((float)v0.w + (float)v1.w) + ((float)v2.w + (float)v3.w);
            accB.x += ((float)v4.x + (float)v5.x) + ((float)v6.x + (float)v7.x);
            accB.y += ((float)v4.y + (float)v5.y) + ((float)v6.y + (float)v7.y);
            accB.z += ((float)v4.z + (float)v5.z) + ((float)v6.z + (float)v7.z);
            accB.w += ((float)v4.w + (float)v5.w) + ((float)v6.w + (float)v7.w);
        }
        for (; e < degc; ++e) {
            int s = bk[e];
            f16x4 v = *(const f16x4*)&cat[(size_t)s * 256 + lane * 4];
            accA.x += (float)v.x; accA.y += (float)v.y;
            accA.z += (float)v.z; accA.w += (float)v.w;
        }
        float4 self = ((const float4*)nf)[(size_t)node * 64 + lane];
        float fd = (float)deg;
        f16x4 o;
        o.x = (_Float16)(fd * self.x - (accA.x + accB.x));
        o.y = (_Float16)(fd * self.y - (accA.y + accB.y));
        o.z = (_Float16)(fd * self.z - (accA.z + accB.z));
        o.w = (_Float16)(fd * self.w - (accA.w + accB.w));
        *(f16x4*)&sA[rw * APAD + 256 + lane * 4] = o;
    }
    __syncthreads();

    // ---- stage 1: h[16][256] = sA @ W1t + b1 ----
    size_t brow[2];
#pragma unroll
    for (int j = 0; j < 2; ++j) brow[j] = (size_t)(wn + j * 16 + fm) * 512 + fk;

    f16x8 wp[4][2];
#pragma unroll
    for (int s = 0; s < 4; ++s)
#pragma unroll
        for (int j = 0; j < 2; ++j)
            wp[s][j] = *(const f16x8*)&W1t[brow[j] + s * 32];

    f32x4 acc[2] = {};
    f16x8 a_cur = *(const f16x8*)&sA[fm * APAD + fk];
#pragma unroll
    for (int kb = 0; kb < 512; kb += 32) {
        int slot = (kb >> 5) & 3;
        f16x8 a_nxt;
        if (kb + 32 < 512) a_nxt = *(const f16x8*)&sA[fm * APAD + kb + 32 + fk];
        f16x8 w0 = wp[slot][0], w1 = wp[slot][1];
        if (kb + 128 < 512) {
            wp[slot][0] = *(const f16x8*)&W1t[brow[0] + kb + 128];
            wp[slot][1] = *(const f16x8*)&W1t[brow[1] + kb + 128];
        }
        acc[0] = __builtin_amdgcn_mfma_f32_16x16x32_f16(a_cur, w0, acc[0], 0, 0, 0);
        acc[1] = __builtin_amdgcn_mfma_f32_16x16x32_f16(a_cur, w1, acc[1], 0, 0, 0);
        if (kb + 32 < 512) a_cur = a_nxt;
    }

    // epilogue 1: hbuf[row][ncol], row = q*4+r, ncol = wn + j*16 + fm
#pragma unroll
    for (int j = 0; j < 2; ++j) {
        int ncol = wn + j * 16 + fm;
        float bv = b1[ncol];
#pragma unroll
        for (int r = 0; r < 4; ++r)
            hbuf[(q * 4 + r) * HPAD + ncol] = (_Float16)(acc[j][r] + bv);
    }
    __syncthreads();

    // ---- stage 2: out[16][256] = tanh(h @ W2t + b2) ----
    size_t brow2[2];
#pragma unroll
    for (int j = 0; j < 2; ++j) brow2[j] = (size_t)(wn + j * 16 + fm) * 256 + fk;

#pragma unroll
    for (int s = 0; s < 4; ++s)
#pragma unroll
        for (int j = 0; j < 2; ++j)
            wp[s][j] = *(const f16x8*)&W2t[brow2[j] + s * 32];

    f32x4 acc2[2] = {};
    a_cur = *(const f16x8*)&hbuf[fm * HPAD + fk];
#pragma unroll
    for (int kb = 0; kb < 256; kb += 32) {
        int slot = (kb >> 5) & 3;
        f16x8 a_nxt;
        if (kb + 32 < 256) a_nxt = *(const f16x8*)&hbuf[fm * HPAD + kb + 32 + fk];
        f16x8 w0 = wp[slot][0], w1 = wp[slot][1];
        if (kb + 128 < 256) {
            wp[slot][0] = *(const f16x8*)&W2t[brow2[0] + kb + 128];
            wp[slot][1] = *(const f16x8*)&W2t[brow2[1] + kb + 128];
        }
        acc2[0] = __builtin_amdgcn_mfma_f32_16x16x32_f16(a_cur, w0, acc2[0], 0, 0, 0);
        acc2[1] = __builtin_amdgcn_mfma_f32_16x16x32_f16(a_cur, w1, acc2[1], 0, 0, 0);
        if (kb + 32 < 256) a_cur = a_nxt;
    }

    // epilogue 2
#pragma unroll
    for (int j = 0; j < 2; ++j) {
        int ncol = wn + j * 16 + fm;
        float bv = b2[ncol];
#pragma unroll
        for (int r = 0; r < 4; ++r) {
            int row = m0 + q * 4 + r;
            if (row < M) out[(size_t)row * 256 + ncol] = tanhf(acc2[j][r] + bv);
        }
    }
}

// ---------------------------------------------------------------------------
extern "C" void kernel_launch(void* const* d_in, const int* in_sizes, int n_in,
                              void* d_out, int out_size, void* d_ws, size_t ws_size,
                              hipStream_t stream) {
    const float* nf  = (const float*)d_in[0];   // [N, 256] fp32
    const float* W1  = (const float*)d_in[1];   // [512, 256]
    const float* b1  = (const float*)d_in[2];   // [256]
    const float* W2  = (const float*)d_in[3];   // [256, 256]
    const float* b2  = (const float*)d_in[4];   // [256]
    const int* esrc  = (const int*)d_in[5];     // [E]
    const int* edst  = (const int*)d_in[6];     // [E]
    float* out = (float*)d_out;                 // [N, 256] fp32

    int N = in_sizes[0] / H2;
    int E = in_sizes[5];

    char* ws = (char*)d_ws;
    size_t off = 0;
    auto take = [&](size_t bytes) { size_t o = off; off += (bytes + 255) / 256 * 256; return o; };
    int*       cursor = (int*)(ws + take((size_t)N * 4));
    int*       bucket = (int*)(ws + take((size_t)N * MAXDEG * 4));
    _Float16*  cat    = (_Float16*)(ws + take((size_t)N * 256 * 2));
    _Float16*  W1t    = (_Float16*)(ws + take(512 * 256 * 2));
    _Float16*  W2t    = (_Float16*)(ws + take(256 * 256 * 2));

    prep<<<(N + 3) / 4, 256, 0, stream>>>(nf, W1, W2, cursor, cat, W1t, W2t, N);
    scatter_edges<<<(E + 255) / 256, 256, 0, stream>>>(esrc, edst, cursor, bucket, E);
    gemm12agg<<<(N + 15) / 16, 512, 0, stream>>>(nf, cat, cursor, bucket,
                                                 W1t, W2t, b1, b2, out, N);
}